// Round 5
// baseline (193.578 us; speedup 1.0000x reference)
//
#include <hip/hip_runtime.h>

typedef unsigned short u16;
typedef unsigned int   u32;
typedef __bf16 bf16x8 __attribute__((ext_vector_type(8)));
typedef float  f32x4  __attribute__((ext_vector_type(4)));

#define DEVI __device__ __forceinline__

DEVI u16 f2bf(float f) {
    union { float f; u32 u; } c; c.f = f;
    u32 u = c.u;
    u32 r = (u + 0x7fffu + ((u >> 16) & 1u)) >> 16;
    return (u16)r;
}
DEVI float bf2f(u16 v) {
    union { u32 u; float f; } c; c.u = ((u32)v) << 16;
    return c.f;
}

DEVI void gload16(const void* g, void* l) {
    __builtin_amdgcn_global_load_lds(
        (const __attribute__((address_space(1))) void*)g,
        (__attribute__((address_space(3))) void*)l, 16, 0, 0);
}

// ---------------- 256x256 8-phase GEMM machinery ----------------
// LDS (u16 units): buffer b at b*32768; within buffer:
//   A kh0 @0, A kh1 @8192, B kh0 @16384, B kh1 @24576
// Each kh-slot: [256 rows][4 chunks of 16B], 64B row stride.
// T2 chunk swizzle: physical chunk p holds logical chunk p^(row&3).
//   - stage: LDS dest linear (gload_lds requirement), global SOURCE column
//     pre-swizzled (rule 21: source permutation == read permutation).
//   - read: physical chunk = (lane>>4) ^ (lane&3).
//   Bank-group (4r+p) mod 8 then covers all 8 groups exactly 8 lanes each
//   (4 per half-wave) -> conflict-free ds_read_b128 by arithmetic.
//
// Sync rule (round-3 race fix): vmcnt is PER-WAVE, but each slot is staged
// by all 8 waves -> every counted VMW sits BEFORE a closing s_barrier.

#define VMW(N)  asm volatile("s_waitcnt vmcnt(" #N ")" ::: "memory")
#define BAR     __builtin_amdgcn_s_barrier()
#define MMP     BAR; asm volatile("s_waitcnt lgkmcnt(0)" ::: "memory"); \
                __builtin_amdgcn_sched_barrier(0); __builtin_amdgcn_s_setprio(1)
#define MME     __builtin_amdgcn_s_setprio(0); BAR
#define MMEV(N) __builtin_amdgcn_s_setprio(0); VMW(N); BAR

// stage one kh half-tile: 256 rows x 32 cols bf16 = 16KB, 2 x 16B per thread
DEVI void stage_kh(const u16* g, u16* slot, int tid) {
    const int K = 1024;
    const int wvb = (tid >> 6) << 9;             // wave base (u16), dest linear
    const int r = tid >> 2;                      // row 0..127 (and +128)
    const int p = tid & 3;                       // physical chunk this lane fills
    const int c = p ^ (r & 3);                   // logical (source) chunk
    const long off = (long)r * K + (c << 3);
    gload16(g + off, slot + wvb);
    gload16(g + off + (long)128 * K, slot + 4096 + wvb);   // row+128: same r&3
}

DEVI void lda4(bf16x8 a[4], const u16* base, int mh) {
#pragma unroll
    for (int q = 0; q < 4; ++q)
        a[q] = *(const bf16x8*)(base + mh * 2048 + q * 512);
}
DEVI void ldb4(bf16x8 b[4], const u16* base) {
#pragma unroll
    for (int n = 0; n < 4; ++n)
        b[n] = *(const bf16x8*)(base + n * 512);
}
DEVI void mm16(f32x4 (&acc)[8][4], const bf16x8 a[4], const bf16x8 b[4], int mh) {
#pragma unroll
    for (int q = 0; q < 4; ++q)
#pragma unroll
        for (int n = 0; n < 4; ++n)
            acc[mh * 4 + q][n] =
                __builtin_amdgcn_mfma_f32_16x16x32_bf16(a[q], b[n], acc[mh * 4 + q][n], 0, 0, 0);
}

// Full K=1024 pipeline: 16 K-tiles, 7 iterations x 8 phases + peeled tail.
DEVI void pipeline(const u16* Ablk, const u16* Bblk, u16* lds,
                   f32x4 (&acc)[8][4], int tid) {
    const int lane = tid & 63;
    const int wm = (tid >> 6) >> 2, wn = (tid >> 6) & 3;
    const int pchunk = ((lane >> 4) ^ (lane & 3)) << 3;    // swizzled chunk (u16)
    const int aoff = wm * 4096 + (lane & 15) * 32 + pchunk;
    const int boff = 16384 + wn * 2048 + (lane & 15) * 32 + pchunk;
    u16* b0 = lds;
    u16* b1 = lds + 32768;

    // prologue: s1..s7 (t1.Akh1 is staged at iter0.ph0)
    stage_kh(Bblk,      b0 + 16384, tid);   // s1 t0.B0
    stage_kh(Ablk,      b0,         tid);   // s2 t0.A0
    stage_kh(Bblk + 32, b0 + 24576, tid);   // s3 t0.B1
    stage_kh(Ablk + 32, b0 + 8192,  tid);   // s4 t0.A1
    stage_kh(Bblk + 64, b1 + 16384, tid);   // s5 t1.B0
    stage_kh(Ablk + 64, b1,         tid);   // s6 t1.A0
    stage_kh(Bblk + 96, b1 + 24576, tid);   // s7 t1.B1
    VMW(10); BAR;                           // gate ph0 reads (s1,s2) globally

    bf16x8 af[4], bfr[4];

#pragma unroll 1
    for (int j = 0; j < 7; ++j) {
        const u16* Aod = Ablk + (2 * j + 1) * 64;
        const u16* At2 = Ablk + (2 * j + 2) * 64;
        const u16* Bt2 = Bblk + (2 * j + 2) * 64;
        // ph0: buf0 kh0 mh0 (+B)   stage t(2j+1).Akh1 -> b1.A1
        lda4(af, b0 + aoff, 0); ldb4(bfr, b0 + boff);
        stage_kh(Aod + 32, b1 + 8192, tid);
        MMP; mm16(acc, af, bfr, 0); MME;
        // ph1: buf0 kh0 mh1        stage t+2.Bkh0 -> b0.B0   [gate ph2]
        lda4(af, b0 + aoff, 1);
        stage_kh(Bt2, b0 + 16384, tid);
        MMP; mm16(acc, af, bfr, 1); MMEV(10);
        // ph2: buf0 kh1 mh0 (+B)   stage t+2.Akh0 -> b0.A0
        lda4(af, b0 + 8192 + aoff, 0); ldb4(bfr, b0 + 8192 + boff);
        stage_kh(At2, b0, tid);
        MMP; mm16(acc, af, bfr, 0); MME;
        // ph3: buf0 kh1 mh1        stage t+2.Bkh1 -> b0.B1   [gate ph4]
        lda4(af, b0 + 8192 + aoff, 1);
        stage_kh(Bt2 + 32, b0 + 24576, tid);
        MMP; mm16(acc, af, bfr, 1); MMEV(10);
        // ph4: buf1 kh0 mh0 (+B)   stage t+2.Akh1 -> b0.A1
        lda4(af, b1 + aoff, 0); ldb4(bfr, b1 + boff);
        stage_kh(At2 + 32, b0 + 8192, tid);
        MMP; mm16(acc, af, bfr, 0); MME;
        // ph5: buf1 kh0 mh1        stage t+3.Bkh0 -> b1.B0   [gate ph6]
        lda4(af, b1 + aoff, 1);
        stage_kh(Bt2 + 64, b1 + 16384, tid);
        MMP; mm16(acc, af, bfr, 1); MMEV(10);
        // ph6: buf1 kh1 mh0 (+B)   stage t+3.Akh0 -> b1.A0
        lda4(af, b1 + 8192 + aoff, 0); ldb4(bfr, b1 + 8192 + boff);
        stage_kh(At2 + 64, b1, tid);
        MMP; mm16(acc, af, bfr, 0); MME;
        // ph7: buf1 kh1 mh1        stage t+3.Bkh1 -> b1.B1   [gate next ph0]
        lda4(af, b1 + 8192 + aoff, 1);
        stage_kh(Bt2 + 96, b1 + 24576, tid);
        MMP; mm16(acc, af, bfr, 1); MMEV(10);
    }
    // peeled tail: tiles 14 (b0), 15 (b1); drain 8 -> 4 -> 0
    {
        const u16* Aod = Ablk + 15 * 64;
        lda4(af, b0 + aoff, 0); ldb4(bfr, b0 + boff);
        stage_kh(Aod + 32, b1 + 8192, tid);           // s64 t15.A1
        MMP; mm16(acc, af, bfr, 0); MME;
        lda4(af, b0 + aoff, 1);
        MMP; mm16(acc, af, bfr, 1); MMEV(8);
        lda4(af, b0 + 8192 + aoff, 0); ldb4(bfr, b0 + 8192 + boff);
        MMP; mm16(acc, af, bfr, 0); MME;
        lda4(af, b0 + 8192 + aoff, 1);
        MMP; mm16(acc, af, bfr, 1); MMEV(4);
        lda4(af, b1 + aoff, 0); ldb4(bfr, b1 + boff);
        MMP; mm16(acc, af, bfr, 0); MME;
        lda4(af, b1 + aoff, 1);
        MMP; mm16(acc, af, bfr, 1); MMEV(0);
        lda4(af, b1 + 8192 + aoff, 0); ldb4(bfr, b1 + 8192 + boff);
        MMP; mm16(acc, af, bfr, 0); MME;
        lda4(af, b1 + 8192 + aoff, 1);
        MMP; mm16(acc, af, bfr, 1); MME;
    }
}

// ---------------- gate GEMM: P = A @ Bcat^T, fused sigmoid-gate epilogue ----
// writes packed ab[row*1024 + ch] = bf16(a) | bf16(b)<<16

__global__ __launch_bounds__(512, 2) void k_gemm_cat8(
    const u16* __restrict__ A, const u16* __restrict__ Bcat,
    const float* __restrict__ gb, const float* __restrict__ ib,
    u32* __restrict__ ab) {
    __shared__ __align__(16) u16 lds[65536];
    const int tid = threadIdx.x, lane = tid & 63;
    const int wm = (tid >> 6) >> 2, wn = (tid >> 6) & 3;

    // bijective XCD swizzle, grid (8, 64) = 512 wg
    int fid = (int)blockIdx.y * 8 + (int)blockIdx.x;
    int swz = (fid & 7) * 64 + (fid >> 3);
    const long bn = swz & 7, bm = swz >> 3;

    f32x4 acc[8][4] = {};
    pipeline(A + bm * 256 * 1024, Bcat + bn * 256 * 1024, lds, acc, tid);

    const long rbase = bm * 256 + wm * 128;
    const int chbase = (int)bn * 128 + wn * 32;
#pragma unroll
    for (int t = 0; t < 2; ++t) {
        int ch = chbase + t * 16 + (lane & 15);
        float g0 = gb[ch], i0 = ib[ch];
#pragma unroll
        for (int m = 0; m < 8; ++m) {
            long row = rbase + m * 16 + ((lane >> 4) << 2);
#pragma unroll
            for (int i = 0; i < 4; ++i) {
                float pg = acc[m][2 * t][i] + g0;
                float pi = acc[m][2 * t + 1][i] + i0;
                float aa = 1.0f / (1.0f + __expf(-pg));
                float bb = (1.0f - aa) * pi;
                ab[(row + i) * 1024 + ch] = (u32)f2bf(aa) | ((u32)f2bf(bb) << 16);
            }
        }
    }
}

// ---------------- final GEMM: out = h @ out_w + x + out_b ----------------

__global__ __launch_bounds__(512, 2) void k_gemm_out8(
    const u16* __restrict__ A, const u16* __restrict__ Bt,
    const float* __restrict__ xres, const float* __restrict__ ob,
    float* __restrict__ out) {
    __shared__ __align__(16) u16 lds[65536];
    const int tid = threadIdx.x, lane = tid & 63;
    const int wm = (tid >> 6) >> 2, wn = (tid >> 6) & 3;

    // bijective XCD swizzle, grid (4, 64) = 256 wg
    int fid = (int)blockIdx.y * 4 + (int)blockIdx.x;
    int swz = (fid & 7) * 32 + (fid >> 3);
    const long bn = swz & 3, bm = swz >> 2;

    f32x4 acc[8][4] = {};
    pipeline(A + bm * 256 * 1024, Bt + bn * 256 * 1024, lds, acc, tid);

    const long rbase = bm * 256 + wm * 128;
    const int cbase = (int)bn * 256 + wn * 64;
#pragma unroll
    for (int n = 0; n < 4; ++n) {
        int col = cbase + n * 16 + (lane & 15);
        float o0 = ob[col];
#pragma unroll
        for (int m = 0; m < 8; ++m) {
            long row = rbase + m * 16 + ((lane >> 4) << 2);
#pragma unroll
            for (int i = 0; i < 4; ++i) {
                long o = (row + i) * 1024 + col;
                out[o] = acc[m][n][i] + o0 + xres[o];
            }
        }
    }
}

// ---------------- conversions ----------------

__global__ __launch_bounds__(256) void k_cvt_x(const float4* __restrict__ x,
                                               uint2* __restrict__ o, int n4) {
    int i = blockIdx.x * 256 + threadIdx.x;
    if (i < n4) {
        float4 v = x[i];
        uint2 r;
        r.x = (u32)f2bf(v.x) | ((u32)f2bf(v.y) << 16);
        r.y = (u32)f2bf(v.z) | ((u32)f2bf(v.w) << 16);
        o[i] = r;
    }
}

__global__ __launch_bounds__(256) void k_transpose_bf(const float* __restrict__ w,
                                                      u16* __restrict__ wt, int R, int C) {
    __shared__ float t[32][33];
    int c0 = blockIdx.x * 32, r0 = blockIdx.y * 32;
    int x = threadIdx.x & 31, y = threadIdx.x >> 5;
    for (int i = y; i < 32; i += 8) t[i][x] = w[(size_t)(r0 + i) * C + c0 + x];
    __syncthreads();
    for (int i = y; i < 32; i += 8) wt[(size_t)(c0 + i) * R + r0 + x] = f2bf(t[x][i]);
}

// Interleaved concat transpose: rows 32t..32t+15 = gate ch 16t..16t+15,
// rows 32t+16..32t+31 = inp, same channels.
__global__ __launch_bounds__(256) void k_transpose_cat(const float* __restrict__ gw,
                                                       const float* __restrict__ iw,
                                                       u16* __restrict__ wt, int K, int C) {
    __shared__ float t[32][33];
    int c0 = blockIdx.x * 32, r0 = blockIdx.y * 32;
    const float* w = blockIdx.z ? iw : gw;
    int x = threadIdx.x & 31, y = threadIdx.x >> 5;
    for (int i = y; i < 32; i += 8) t[i][x] = w[(size_t)(r0 + i) * C + c0 + x];
    __syncthreads();
    for (int i = y; i < 32; i += 8) {
        int ch = c0 + i;
        int r = ((ch >> 4) << 5) | ((int)blockIdx.z << 4) | (ch & 15);
        wt[(size_t)r * K + r0 + x] = f2bf(t[x][i]);
    }
}

// ---------------- chunked affine scan (packed ab stream) ----------------
// ab[row*1024 + ch]: lo = a (bf16), hi = b (bf16). h_t = a*h + b over s.

__global__ __launch_bounds__(256) void k_scanA(const u32* __restrict__ ab,
                                               float2* __restrict__ cAB) {
    int e = blockIdx.x * 256 + threadIdx.x;  // 0..1023
    int c = blockIdx.y, bt = blockIdx.z;
    long base = ((long)bt * 4096 + c * 64) * 1024 + e;
    float Aa = 1.f, H = 0.f;
#pragma unroll 4
    for (int i = 0; i < 64; ++i) {
        u32 v = ab[base + (long)i * 1024];
        float a = bf2f((u16)v), b = bf2f((u16)(v >> 16));
        H = a * H + b;
        Aa *= a;
    }
    cAB[((long)bt * 64 + c) * 1024 + e] = make_float2(Aa, H);
}

__global__ __launch_bounds__(256) void k_scanB(const float2* __restrict__ cAB,
                                               float* __restrict__ hin) {
    int e = blockIdx.x * 256 + threadIdx.x;
    int bt = blockIdx.y;
    float H = 0.f;
#pragma unroll
    for (int c = 0; c < 64; ++c) {
        long s = ((long)bt * 64 + c) * 1024 + e;
        hin[s] = H;
        float2 v = cAB[s];
        H = v.x * H + v.y;
    }
}

__global__ __launch_bounds__(256) void k_scanC(const u32* __restrict__ ab,
                                               const float* __restrict__ hin,
                                               u16* __restrict__ hout) {
    int e = blockIdx.x * 256 + threadIdx.x;
    int c = blockIdx.y, bt = blockIdx.z;
    long base = ((long)bt * 4096 + c * 64) * 1024 + e;
    float H = hin[((long)bt * 64 + c) * 1024 + e];
#pragma unroll 4
    for (int i = 0; i < 64; ++i) {
        u32 v = ab[base + (long)i * 1024];
        H = bf2f((u16)v) * H + bf2f((u16)(v >> 16));
        hout[base + (long)i * 1024] = f2bf(H);
    }
}

// ---------------- launch ----------------

extern "C" void kernel_launch(void* const* d_in, const int* in_sizes, int n_in,
                              void* d_out, int out_size, void* d_ws, size_t ws_size,
                              hipStream_t stream) {
    const float* x      = (const float*)d_in[0];
    const float* gate_w = (const float*)d_in[1];
    const float* gate_b = (const float*)d_in[2];
    const float* inp_w  = (const float*)d_in[3];
    const float* inp_b  = (const float*)d_in[4];
    const float* out_w  = (const float*)d_in[5];
    const float* out_b  = (const float*)d_in[6];
    float* out = (float*)d_out;

    const int Bsz = 4, S = 4096, Din = 1024, Dst = 1024;
    const int M = Bsz * S;                 // 16384
    const long nx = (long)M * Din;         // 16777216

    // workspace layout (bytes)
    char* w = (char*)d_ws;
    u16* xb      = (u16*)(w);                // 33,554,432  x bf16
    u16* catW    = (u16*)(w + 33554432);     //  4,194,304  [gate;inp] interleaved ^T
    u16* owT     = (u16*)(w + 37748736);     //  2,097,152  out_w^T bf16
    u16* hbf     = (u16*)(w + 39845888);     // 33,554,432  scan_out bf16
    float2* cAB  = (float2*)(w + 73400320);  //  2,097,152  chunk (A,H) pairs
    float* hin   = (float*)(w + 75497472);   //  1,048,576  chunk incoming states
    // total 76,546,048 B

    // packed ab lives in d_out (67,108,864 B); overwritten by final GEMM.
    u32* ab = (u32*)d_out;

    // 1. conversions
    k_cvt_x<<<(int)(nx / 4 / 256), 256, 0, stream>>>((const float4*)x, (uint2*)xb, (int)(nx / 4));
    k_transpose_cat<<<dim3(Dst / 32, Din / 32, 2), 256, 0, stream>>>(gate_w, inp_w, catW, Din, Dst);
    k_transpose_bf<<<dim3(Din / 32, Dst / 32), 256, 0, stream>>>(out_w, owT, Dst, Din);

    // 2. fused concat GEMM -> packed ab
    k_gemm_cat8<<<dim3(8, M / 256), 512, 0, stream>>>(xb, catW, gate_b, inp_b, ab);

    // 3. chunked scan -> h (bf16)
    k_scanA<<<dim3(4, 64, Bsz), 256, 0, stream>>>(ab, cAB);
    k_scanB<<<dim3(4, Bsz), 256, 0, stream>>>(cAB, hin);
    k_scanC<<<dim3(4, 64, Bsz), 256, 0, stream>>>(ab, hin, hbf);

    // 4. final GEMM: out = h @ out_w + x + out_b
    k_gemm_out8<<<dim3(4, M / 256), 512, 0, stream>>>(hbf, owT, x, out_b, out);
}

// Round 6
// 184.526 us; speedup vs baseline: 1.0491x; 1.0491x over previous
//
#include <hip/hip_runtime.h>

typedef unsigned short u16;
typedef unsigned int   u32;
typedef __bf16 bf16x8 __attribute__((ext_vector_type(8)));
typedef float  f32x4  __attribute__((ext_vector_type(4)));

#define DEVI __device__ __forceinline__

DEVI u16 f2bf(float f) {
    union { float f; u32 u; } c; c.f = f;
    u32 u = c.u;
    u32 r = (u + 0x7fffu + ((u >> 16) & 1u)) >> 16;
    return (u16)r;
}
DEVI float bf2f(u16 v) {
    union { u32 u; float f; } c; c.u = ((u32)v) << 16;
    return c.f;
}

DEVI void gload16(const void* g, void* l) {
    __builtin_amdgcn_global_load_lds(
        (const __attribute__((address_space(1))) void*)g,
        (__attribute__((address_space(3))) void*)l, 16, 0, 0);
}

// ---------------- 256x256 software-pipelined GEMM ----------------
// LDS slots (u16 offsets), each slot = 256 rows x 32 K (16KB):
//   b0: A.k0 @0, A.k1 @8192, B.k0 @16384, B.k1 @24576
//   b1: A.k0 @32768, A.k1 @40960, B.k0 @49152, B.k1 @57344
// Schedule: 8 phases per 2 K-tiles. ONE barrier per phase. A-fragments
// register-prefetched one phase ahead (afA/afB alternate); B read in-phase
// (issued first -> max latency headroom before MFMA consumes it). No
// explicit lgkmcnt: compiler emits counted waits, leaving the prefetch
// reads in flight under the MFMA cluster.
// Stage->read gap is uniformly 5 phases; VMW(8) at every phase close
// (before the barrier -- vmcnt is per-wave, barrier globalizes) completes
// exactly the stage needed <=2 phases later. Tail drains 8 -> 4 -> 0.

#define VMW(N)  asm volatile("s_waitcnt vmcnt(" #N ")" ::: "memory")
#define BAR     __builtin_amdgcn_s_barrier()
#define SP1     __builtin_amdgcn_s_setprio(1)
#define SP0     __builtin_amdgcn_s_setprio(0)
#define CLOSE(N) __builtin_amdgcn_sched_barrier(0); VMW(N); BAR
#define CLOSEB   __builtin_amdgcn_sched_barrier(0); BAR

// stage one kh half-tile: 256 rows x 32 cols bf16 = 16KB, 2 x 16B per thread
DEVI void stage_kh(const u16* g, u16* slot, int tid) {
    const int K = 1024;
    const int wvb = (tid >> 6) << 9;             // wave base (u16), dest linear
    const int r = tid >> 2;                      // row 0..127 (and +128)
    const int p = tid & 3;                       // physical chunk this lane fills
    const int c = p ^ (r & 3);                   // logical (source) chunk
    const long off = (long)r * K + (c << 3);
    gload16(g + off, slot + wvb);
    gload16(g + off + (long)128 * K, slot + 4096 + wvb);
}

DEVI void ld4(bf16x8 (&d)[4], const u16* p) {
#pragma unroll
    for (int q = 0; q < 4; ++q) d[q] = *(const bf16x8*)(p + q * 512);
}
DEVI void mm16(f32x4 (&acc)[8][4], const bf16x8 a[4], const bf16x8 b[4], int mh) {
#pragma unroll
    for (int q = 0; q < 4; ++q)
#pragma unroll
        for (int n = 0; n < 4; ++n)
            acc[mh * 4 + q][n] =
                __builtin_amdgcn_mfma_f32_16x16x32_bf16(a[q], b[n], acc[mh * 4 + q][n], 0, 0, 0);
}

DEVI void pipeline(const u16* Ablk, const u16* Bblk, u16* lds,
                   f32x4 (&acc)[8][4], int tid) {
    const int lane = tid & 63;
    const int wm = (tid >> 6) >> 2, wn = (tid >> 6) & 3;
    const int pch = ((lane >> 4) ^ (lane & 3)) << 3;     // chunk swizzle (u16)
    const int aoff = wm * 4096 + (lane & 15) * 32 + pch; // slot-relative
    const int boff = wn * 2048 + (lane & 15) * 32 + pch; // slot-relative

    // prologue: t0 full + t1.{B0,A0,B1}
    stage_kh(Bblk,      lds + 16384, tid);   // s1 t0.B0
    stage_kh(Ablk,      lds + 0,     tid);   // s2 t0.A0
    stage_kh(Bblk + 32, lds + 24576, tid);   // s3 t0.B1
    stage_kh(Ablk + 32, lds + 8192,  tid);   // s4 t0.A1
    stage_kh(Bblk + 64, lds + 49152, tid);   // s5 t1.B0
    stage_kh(Ablk + 64, lds + 32768, tid);   // s6 t1.A0
    stage_kh(Bblk + 96, lds + 57344, tid);   // s7 t1.B1
    VMW(10); BAR;                            // s1,s2 landed globally

    bf16x8 afA[4], afB[4], bfr[4];
    ld4(afA, lds + aoff);                    // A(b0,k0,m0) for ph0

#pragma unroll 1
    for (int j = 0; j < 7; ++j) {
        const u16* Aod = Ablk + (2 * j + 1) * 64;
        const u16* At2 = Ablk + (2 * j + 2) * 64;
        const u16* Bt2 = Bblk + (2 * j + 2) * 64;
        // ph0: MFMA(b0,k0,m0)  prefetch A(b0,k0,m1)  stage t(2j+1).A1
        ld4(bfr, lds + 16384 + boff);
        ld4(afB, lds + 2048 + aoff);
        stage_kh(Aod + 32, lds + 40960, tid);
        SP1; mm16(acc, afA, bfr, 0); SP0; CLOSE(8);
        // ph1: MFMA(b0,k0,m1)  prefetch A(b0,k1,m0)  stage t+2.B0
        ld4(afA, lds + 8192 + aoff);
        stage_kh(Bt2, lds + 16384, tid);
        SP1; mm16(acc, afB, bfr, 1); SP0; CLOSE(8);
        // ph2: MFMA(b0,k1,m0)  B(b0,k1)  prefetch A(b0,k1,m1)  stage t+2.A0
        ld4(bfr, lds + 24576 + boff);
        ld4(afB, lds + 10240 + aoff);
        stage_kh(At2, lds + 0, tid);
        SP1; mm16(acc, afA, bfr, 0); SP0; CLOSE(8);
        // ph3: MFMA(b0,k1,m1)  prefetch A(b1,k0,m0)  stage t+2.B1
        ld4(afA, lds + 32768 + aoff);
        stage_kh(Bt2 + 32, lds + 24576, tid);
        SP1; mm16(acc, afB, bfr, 1); SP0; CLOSE(8);
        // ph4: MFMA(b1,k0,m0)  B(b1,k0)  prefetch A(b1,k0,m1)  stage t+2.A1
        ld4(bfr, lds + 49152 + boff);
        ld4(afB, lds + 34816 + aoff);
        stage_kh(At2 + 32, lds + 8192, tid);
        SP1; mm16(acc, afA, bfr, 0); SP0; CLOSE(8);
        // ph5: MFMA(b1,k0,m1)  prefetch A(b1,k1,m0)  stage t+3.B0
        ld4(afA, lds + 40960 + aoff);
        stage_kh(Bt2 + 64, lds + 49152, tid);
        SP1; mm16(acc, afB, bfr, 1); SP0; CLOSE(8);
        // ph6: MFMA(b1,k1,m0)  B(b1,k1)  prefetch A(b1,k1,m1)  stage t+3.A0
        ld4(bfr, lds + 57344 + boff);
        ld4(afB, lds + 43008 + aoff);
        stage_kh(At2 + 64, lds + 32768, tid);
        SP1; mm16(acc, afA, bfr, 0); SP0; CLOSE(8);
        // ph7: MFMA(b1,k1,m1)  prefetch next A(b0,k0,m0)  stage t+3.B1
        ld4(afA, lds + aoff);
        stage_kh(Bt2 + 96, lds + 57344, tid);
        SP1; mm16(acc, afB, bfr, 1); SP0; CLOSE(8);
    }
    // tail: t14 (b0), t15 (b1); only stage = t15.A1; drain 8 -> 4 -> 0
    {
        const u16* Aod = Ablk + 15 * 64;
        // tp0
        ld4(bfr, lds + 16384 + boff);
        ld4(afB, lds + 2048 + aoff);
        stage_kh(Aod + 32, lds + 40960, tid);
        SP1; mm16(acc, afA, bfr, 0); SP0; CLOSE(8);
        // tp1
        ld4(afA, lds + 8192 + aoff);
        SP1; mm16(acc, afB, bfr, 1); SP0; CLOSEB;
        // tp2
        ld4(bfr, lds + 24576 + boff);
        ld4(afB, lds + 10240 + aoff);
        SP1; mm16(acc, afA, bfr, 0); SP0; CLOSE(4);
        // tp3
        ld4(afA, lds + 32768 + aoff);
        SP1; mm16(acc, afB, bfr, 1); SP0; CLOSEB;
        // tp4
        ld4(bfr, lds + 49152 + boff);
        ld4(afB, lds + 34816 + aoff);
        SP1; mm16(acc, afA, bfr, 0); SP0; CLOSE(0);
        // tp5
        ld4(afA, lds + 40960 + aoff);
        SP1; mm16(acc, afB, bfr, 1); SP0; CLOSEB;
        // tp6
        ld4(bfr, lds + 57344 + boff);
        ld4(afB, lds + 43008 + aoff);
        SP1; mm16(acc, afA, bfr, 0); SP0; CLOSEB;
        // tp7
        SP1; mm16(acc, afB, bfr, 1); SP0;
    }
}

// ---------------- gate GEMM: P = A @ Bcat^T, fused sigmoid-gate epilogue ----
// writes packed ab[row*1024 + ch] = bf16(a) | bf16(b)<<16

__global__ __launch_bounds__(512, 2) void k_gemm_cat8(
    const u16* __restrict__ A, const u16* __restrict__ Bcat,
    const float* __restrict__ gb, const float* __restrict__ ib,
    u32* __restrict__ ab) {
    __shared__ __align__(16) u16 lds[65536];
    const int tid = threadIdx.x, lane = tid & 63;
    const int wm = (tid >> 6) >> 2, wn = (tid >> 6) & 3;

    // bijective XCD swizzle, grid (8, 64) = 512 wg
    int fid = (int)blockIdx.y * 8 + (int)blockIdx.x;
    int swz = (fid & 7) * 64 + (fid >> 3);
    const long bn = swz & 7, bm = swz >> 3;

    f32x4 acc[8][4] = {};
    pipeline(A + bm * 256 * 1024, Bcat + bn * 256 * 1024, lds, acc, tid);

    const long rbase = bm * 256 + wm * 128;
    const int chbase = (int)bn * 128 + wn * 32;
#pragma unroll
    for (int t = 0; t < 2; ++t) {
        int ch = chbase + t * 16 + (lane & 15);
        float g0 = gb[ch], i0 = ib[ch];
#pragma unroll
        for (int m = 0; m < 8; ++m) {
            long row = rbase + m * 16 + ((lane >> 4) << 2);
#pragma unroll
            for (int i = 0; i < 4; ++i) {
                float pg = acc[m][2 * t][i] + g0;
                float pi = acc[m][2 * t + 1][i] + i0;
                float aa = 1.0f / (1.0f + __expf(-pg));
                float bb = (1.0f - aa) * pi;
                ab[(row + i) * 1024 + ch] = (u32)f2bf(aa) | ((u32)f2bf(bb) << 16);
            }
        }
    }
}

// ---------------- final GEMM: out = h @ out_w + x + out_b ----------------

__global__ __launch_bounds__(512, 2) void k_gemm_out8(
    const u16* __restrict__ A, const u16* __restrict__ Bt,
    const float* __restrict__ xres, const float* __restrict__ ob,
    float* __restrict__ out) {
    __shared__ __align__(16) u16 lds[65536];
    const int tid = threadIdx.x, lane = tid & 63;
    const int wm = (tid >> 6) >> 2, wn = (tid >> 6) & 3;

    // bijective XCD swizzle, grid (4, 64) = 256 wg
    int fid = (int)blockIdx.y * 4 + (int)blockIdx.x;
    int swz = (fid & 7) * 32 + (fid >> 3);
    const long bn = swz & 3, bm = swz >> 2;

    f32x4 acc[8][4] = {};
    pipeline(A + bm * 256 * 1024, Bt + bn * 256 * 1024, lds, acc, tid);

    const long rbase = bm * 256 + wm * 128;
    const int cbase = (int)bn * 256 + wn * 64;
#pragma unroll
    for (int n = 0; n < 4; ++n) {
        int col = cbase + n * 16 + (lane & 15);
        float o0 = ob[col];
#pragma unroll
        for (int m = 0; m < 8; ++m) {
            long row = rbase + m * 16 + ((lane >> 4) << 2);
#pragma unroll
            for (int i = 0; i < 4; ++i) {
                long o = (row + i) * 1024 + col;
                out[o] = acc[m][n][i] + o0 + xres[o];
            }
        }
    }
}

// ---------------- conversions ----------------

__global__ __launch_bounds__(256) void k_cvt_x(const float4* __restrict__ x,
                                               uint2* __restrict__ o, int n4) {
    int i = blockIdx.x * 256 + threadIdx.x;
    if (i < n4) {
        float4 v = x[i];
        uint2 r;
        r.x = (u32)f2bf(v.x) | ((u32)f2bf(v.y) << 16);
        r.y = (u32)f2bf(v.z) | ((u32)f2bf(v.w) << 16);
        o[i] = r;
    }
}

__global__ __launch_bounds__(256) void k_transpose_bf(const float* __restrict__ w,
                                                      u16* __restrict__ wt, int R, int C) {
    __shared__ float t[32][33];
    int c0 = blockIdx.x * 32, r0 = blockIdx.y * 32;
    int x = threadIdx.x & 31, y = threadIdx.x >> 5;
    for (int i = y; i < 32; i += 8) t[i][x] = w[(size_t)(r0 + i) * C + c0 + x];
    __syncthreads();
    for (int i = y; i < 32; i += 8) wt[(size_t)(c0 + i) * R + r0 + x] = f2bf(t[x][i]);
}

// Interleaved concat transpose: rows 32t..32t+15 = gate ch 16t..16t+15,
// rows 32t+16..32t+31 = inp, same channels.
__global__ __launch_bounds__(256) void k_transpose_cat(const float* __restrict__ gw,
                                                       const float* __restrict__ iw,
                                                       u16* __restrict__ wt, int K, int C) {
    __shared__ float t[32][33];
    int c0 = blockIdx.x * 32, r0 = blockIdx.y * 32;
    const float* w = blockIdx.z ? iw : gw;
    int x = threadIdx.x & 31, y = threadIdx.x >> 5;
    for (int i = y; i < 32; i += 8) t[i][x] = w[(size_t)(r0 + i) * C + c0 + x];
    __syncthreads();
    for (int i = y; i < 32; i += 8) {
        int ch = c0 + i;
        int r = ((ch >> 4) << 5) | ((int)blockIdx.z << 4) | (ch & 15);
        wt[(size_t)r * K + r0 + x] = f2bf(t[x][i]);
    }
}

// ---------------- chunked affine scan (packed ab stream) ----------------
// ab[row*1024 + ch]: lo = a (bf16), hi = b (bf16). h_t = a*h + b over s.

__global__ __launch_bounds__(256) void k_scanA(const u32* __restrict__ ab,
                                               float2* __restrict__ cAB) {
    int e = blockIdx.x * 256 + threadIdx.x;  // 0..1023
    int c = blockIdx.y, bt = blockIdx.z;
    long base = ((long)bt * 4096 + c * 64) * 1024 + e;
    float Aa = 1.f, H = 0.f;
#pragma unroll 4
    for (int i = 0; i < 64; ++i) {
        u32 v = ab[base + (long)i * 1024];
        float a = bf2f((u16)v), b = bf2f((u16)(v >> 16));
        H = a * H + b;
        Aa *= a;
    }
    cAB[((long)bt * 64 + c) * 1024 + e] = make_float2(Aa, H);
}

__global__ __launch_bounds__(256) void k_scanB(const float2* __restrict__ cAB,
                                               float* __restrict__ hin) {
    int e = blockIdx.x * 256 + threadIdx.x;
    int bt = blockIdx.y;
    float H = 0.f;
#pragma unroll
    for (int c = 0; c < 64; ++c) {
        long s = ((long)bt * 64 + c) * 1024 + e;
        hin[s] = H;
        float2 v = cAB[s];
        H = v.x * H + v.y;
    }
}

__global__ __launch_bounds__(256) void k_scanC(const u32* __restrict__ ab,
                                               const float* __restrict__ hin,
                                               u16* __restrict__ hout) {
    int e = blockIdx.x * 256 + threadIdx.x;
    int c = blockIdx.y, bt = blockIdx.z;
    long base = ((long)bt * 4096 + c * 64) * 1024 + e;
    float H = hin[((long)bt * 64 + c) * 1024 + e];
#pragma unroll 4
    for (int i = 0; i < 64; ++i) {
        u32 v = ab[base + (long)i * 1024];
        H = bf2f((u16)v) * H + bf2f((u16)(v >> 16));
        hout[base + (long)i * 1024] = f2bf(H);
    }
}

// ---------------- launch ----------------

extern "C" void kernel_launch(void* const* d_in, const int* in_sizes, int n_in,
                              void* d_out, int out_size, void* d_ws, size_t ws_size,
                              hipStream_t stream) {
    const float* x      = (const float*)d_in[0];
    const float* gate_w = (const float*)d_in[1];
    const float* gate_b = (const float*)d_in[2];
    const float* inp_w  = (const float*)d_in[3];
    const float* inp_b  = (const float*)d_in[4];
    const float* out_w  = (const float*)d_in[5];
    const float* out_b  = (const float*)d_in[6];
    float* out = (float*)d_out;

    const int Bsz = 4, S = 4096, Din = 1024, Dst = 1024;
    const int M = Bsz * S;                 // 16384
    const long nx = (long)M * Din;         // 16777216

    // workspace layout (bytes)
    char* w = (char*)d_ws;
    u16* xb      = (u16*)(w);                // 33,554,432  x bf16
    u16* catW    = (u16*)(w + 33554432);     //  4,194,304  [gate;inp] interleaved ^T
    u16* owT     = (u16*)(w + 37748736);     //  2,097,152  out_w^T bf16
    u16* hbf     = (u16*)(w + 39845888);     // 33,554,432  scan_out bf16
    float2* cAB  = (float2*)(w + 73400320);  //  2,097,152  chunk (A,H) pairs
    float* hin   = (float*)(w + 75497472);   //  1,048,576  chunk incoming states
    // total 76,546,048 B

    // packed ab lives in d_out (67,108,864 B); overwritten by final GEMM.
    u32* ab = (u32*)d_out;

    // 1. conversions
    k_cvt_x<<<(int)(nx / 4 / 256), 256, 0, stream>>>((const float4*)x, (uint2*)xb, (int)(nx / 4));
    k_transpose_cat<<<dim3(Dst / 32, Din / 32, 2), 256, 0, stream>>>(gate_w, inp_w, catW, Din, Dst);
    k_transpose_bf<<<dim3(Din / 32, Dst / 32), 256, 0, stream>>>(out_w, owT, Dst, Din);

    // 2. fused concat GEMM -> packed ab
    k_gemm_cat8<<<dim3(8, M / 256), 512, 0, stream>>>(xb, catW, gate_b, inp_b, ab);

    // 3. chunked scan -> h (bf16)
    k_scanA<<<dim3(4, 64, Bsz), 256, 0, stream>>>(ab, cAB);
    k_scanB<<<dim3(4, Bsz), 256, 0, stream>>>(cAB, hin);
    k_scanC<<<dim3(4, 64, Bsz), 256, 0, stream>>>(ab, hin, hbf);

    // 4. final GEMM: out = h @ out_w + x + out_b
    k_gemm_out8<<<dim3(4, M / 256), 512, 0, stream>>>(hbf, owT, x, out_b, out);
}

// Round 7
// 183.131 us; speedup vs baseline: 1.0570x; 1.0076x over previous
//
#include <hip/hip_runtime.h>

typedef unsigned short u16;
typedef unsigned int   u32;
typedef __bf16 bf16x8 __attribute__((ext_vector_type(8)));
typedef float  f32x4  __attribute__((ext_vector_type(4)));

#define DEVI __device__ __forceinline__

DEVI u16 f2bf(float f) {
    union { float f; u32 u; } c; c.f = f;
    u32 u = c.u;
    u32 r = (u + 0x7fffu + ((u >> 16) & 1u)) >> 16;
    return (u16)r;
}
DEVI float bf2f(u16 v) {
    union { u32 u; float f; } c; c.u = ((u32)v) << 16;
    return c.f;
}

DEVI void gload16(const void* g, void* l) {
    __builtin_amdgcn_global_load_lds(
        (const __attribute__((address_space(1))) void*)g,
        (__attribute__((address_space(3))) void*)l, 16, 0, 0);
}

// ---------------- BK=32 occupancy-2 GEMM machinery ----------------
// Slot layout [R rows][4 chunks of 16B], 64B row stride; chunk swizzle:
// physical chunk p holds logical chunk p^(row&3); read chunk (lane>>4)^(lane&3).
// One barrier + one vmcnt gate per K-tile; vmcnt sits BEFORE the barrier
// (vmcnt is per-wave; the barrier globalizes completion — round-3 lesson).

#define VMW(N)  asm volatile("s_waitcnt vmcnt(" #N ")" ::: "memory")
#define BARF    do { asm volatile("" ::: "memory"); __builtin_amdgcn_s_barrier(); \
                     asm volatile("" ::: "memory"); } while (0)
#define SP1     __builtin_amdgcn_s_setprio(1)
#define SP0     __builtin_amdgcn_s_setprio(0)

// stage 256 rows x 32 cols bf16 (16KB): 2 x 16B per thread
DEVI void stage_kh(const u16* g, u16* slot, int tid) {
    const int wvb = (tid >> 6) << 9;             // wave base (u16), dest linear
    const int r = tid >> 2;                      // row 0..127 (and +128)
    const int p = tid & 3;
    const int c = p ^ (r & 3);                   // pre-swizzled source chunk
    const long off = (long)r * 1024 + (c << 3);
    gload16(g + off, slot + wvb);
    gload16(g + off + (long)128 * 1024, slot + 4096 + wvb);
}
// stage 128 rows x 32 cols bf16 (8KB): 1 x 16B per thread
DEVI void stage_a128(const u16* g, u16* slot, int tid) {
    const int wvb = (tid >> 6) << 9;
    const int r = tid >> 2;
    const int p = tid & 3;
    const int c = p ^ (r & 3);
    gload16(g + (long)r * 1024 + (c << 3), slot + wvb);
}

DEVI void ld4(bf16x8 (&d)[4], const u16* p) {
#pragma unroll
    for (int q = 0; q < 4; ++q) d[q] = *(const bf16x8*)(p + q * 512);
}
DEVI void mm16(f32x4 (&acc)[8][4], const bf16x8 a[4], const bf16x8 b[4], int mh) {
#pragma unroll
    for (int q = 0; q < 4; ++q)
#pragma unroll
        for (int n = 0; n < 4; ++n)
            acc[mh * 4 + q][n] =
                __builtin_amdgcn_mfma_f32_16x16x32_bf16(a[q], b[n], acc[mh * 4 + q][n], 0, 0, 0);
}
DEVI void mm4(f32x4 (&acc)[4][4], const bf16x8 a[4], const bf16x8 b[4]) {
#pragma unroll
    for (int q = 0; q < 4; ++q)
#pragma unroll
        for (int n = 0; n < 4; ++n)
            acc[q][n] =
                __builtin_amdgcn_mfma_f32_16x16x32_bf16(a[q], b[n], acc[q][n], 0, 0, 0);
}

// 256x256 tile, BK=32, 2 buffers (64KB), 32 K-tiles.
// Buffer b: A slot @ b*16384, B slot @ b*16384+8192 (u16 units).
DEVI void pipe256(const u16* Ab, const u16* Bb, u16* lds,
                  f32x4 (&acc)[8][4], int tid) {
    const int lane = tid & 63;
    const int wm = (tid >> 6) >> 2, wn = (tid >> 6) & 3;
    const int pch = ((lane >> 4) ^ (lane & 3)) << 3;
    const int aoff = wm * 4096 + (lane & 15) * 32 + pch;
    const int boff = 8192 + wn * 2048 + (lane & 15) * 32 + pch;

    stage_kh(Ab, lds, tid);                  // t0.A -> buf0
    stage_kh(Bb, lds + 8192, tid);           // t0.B
    VMW(0); BARF;

    bf16x8 af0[4], af1[4], bfr[4];
#pragma unroll 1
    for (int j = 0; j < 15; ++j) {
        const u16* gA1 = Ab + (2 * j + 1) * 32;
        const u16* gB1 = Bb + (2 * j + 1) * 32;
        const u16* gA2 = Ab + (2 * j + 2) * 32;
        const u16* gB2 = Bb + (2 * j + 2) * 32;
        // tile 2j (buf0): stage t+1 -> buf1
        stage_kh(gA1, lds + 16384, tid);
        stage_kh(gB1, lds + 24576, tid);
        ld4(bfr, lds + boff);
        ld4(af0, lds + aoff);
        ld4(af1, lds + 2048 + aoff);
        SP1; mm16(acc, af0, bfr, 0); mm16(acc, af1, bfr, 1); SP0;
        VMW(0); BARF;
        // tile 2j+1 (buf1): stage t+2 -> buf0
        stage_kh(gA2, lds, tid);
        stage_kh(gB2, lds + 8192, tid);
        ld4(bfr, lds + 16384 + boff);
        ld4(af0, lds + 16384 + aoff);
        ld4(af1, lds + 18432 + aoff);
        SP1; mm16(acc, af0, bfr, 0); mm16(acc, af1, bfr, 1); SP0;
        VMW(0); BARF;
    }
    // tile 30 (buf0): stage t31 -> buf1
    stage_kh(Ab + 31 * 32, lds + 16384, tid);
    stage_kh(Bb + 31 * 32, lds + 24576, tid);
    ld4(bfr, lds + boff);
    ld4(af0, lds + aoff);
    ld4(af1, lds + 2048 + aoff);
    SP1; mm16(acc, af0, bfr, 0); mm16(acc, af1, bfr, 1); SP0;
    VMW(0); BARF;
    // tile 31 (buf1)
    ld4(bfr, lds + 16384 + boff);
    ld4(af0, lds + 16384 + aoff);
    ld4(af1, lds + 18432 + aoff);
    SP1; mm16(acc, af0, bfr, 0); mm16(acc, af1, bfr, 1); SP0;
}

// 128x256 tile, BK=32, 3 buffers (72KB), 32 K-tiles, counted vmcnt(3).
// Buffer: A slot @ base (4096 u16), B slot @ base+4096 (8192 u16); stride 12288.
DEVI void pipe128(const u16* Ab, const u16* Bb, u16* lds,
                  f32x4 (&acc)[4][4], int tid) {
    const int lane = tid & 63;
    const int wm = (tid >> 6) >> 2, wn = (tid >> 6) & 3;
    const int pch = ((lane >> 4) ^ (lane & 3)) << 3;
    const int aoff = wm * 2048 + (lane & 15) * 32 + pch;
    const int boff = 4096 + wn * 2048 + (lane & 15) * 32 + pch;
    u16* p0 = lds;
    u16* p1 = lds + 12288;
    u16* p2 = lds + 24576;

    stage_a128(Ab, p0, tid);       stage_kh(Bb, p0 + 4096, tid);        // t0
    stage_a128(Ab + 32, p1, tid);  stage_kh(Bb + 32, p1 + 4096, tid);   // t1
    VMW(3); BARF;                  // t0 landed; t1 (3 loads) in flight

    bf16x8 af[4], bfr[4];
#pragma unroll 1
    for (int t = 0; t < 30; ++t) {
        stage_a128(Ab + (t + 2) * 32, p2, tid);
        stage_kh(Bb + (t + 2) * 32, p2 + 4096, tid);
        ld4(bfr, p0 + boff);
        ld4(af, p0 + aoff);
        SP1; mm4(acc, af, bfr); SP0;
        VMW(3); BARF;              // completes t+1; keeps t+2 (3) in flight
        u16* tmp = p0; p0 = p1; p1 = p2; p2 = tmp;
    }
    // tile 30: no stage; drain for t31
    ld4(bfr, p0 + boff);
    ld4(af, p0 + aoff);
    SP1; mm4(acc, af, bfr); SP0;
    VMW(0); BARF;
    // tile 31
    ld4(bfr, p1 + boff);
    ld4(af, p1 + aoff);
    SP1; mm4(acc, af, bfr); SP0;
}

// ---------------- gate GEMM: P = A @ Bcat^T, fused sigmoid-gate epilogue ----
// writes packed ab[row*1024 + ch] = bf16(a) | bf16(b)<<16

__global__ __launch_bounds__(512, 2) void k_gemm_cat8(
    const u16* __restrict__ A, const u16* __restrict__ Bcat,
    const float* __restrict__ gb, const float* __restrict__ ib,
    u32* __restrict__ ab) {
    __shared__ __align__(16) u16 lds[32768];        // 64KB -> 2 blocks/CU
    const int tid = threadIdx.x, lane = tid & 63;
    const int wm = (tid >> 6) >> 2, wn = (tid >> 6) & 3;

    // bijective XCD swizzle, grid (8, 64) = 512 wg
    int fid = (int)blockIdx.y * 8 + (int)blockIdx.x;
    int swz = (fid & 7) * 64 + (fid >> 3);
    const long bn = swz & 7, bm = swz >> 3;

    f32x4 acc[8][4] = {};
    pipe256(A + bm * 256 * 1024, Bcat + bn * 256 * 1024, lds, acc, tid);

    const long rbase = bm * 256 + wm * 128;
    const int chbase = (int)bn * 128 + wn * 32;
#pragma unroll
    for (int t = 0; t < 2; ++t) {
        int ch = chbase + t * 16 + (lane & 15);
        float g0 = gb[ch], i0 = ib[ch];
#pragma unroll
        for (int m = 0; m < 8; ++m) {
            long row = rbase + m * 16 + ((lane >> 4) << 2);
#pragma unroll
            for (int i = 0; i < 4; ++i) {
                float pg = acc[m][2 * t][i] + g0;
                float pi = acc[m][2 * t + 1][i] + i0;
                float aa = 1.0f / (1.0f + __expf(-pg));
                float bb = (1.0f - aa) * pi;
                ab[(row + i) * 1024 + ch] = (u32)f2bf(aa) | ((u32)f2bf(bb) << 16);
            }
        }
    }
}

// ---------------- final GEMM: out = h @ out_w + x + out_b (BM=128) ----------

__global__ __launch_bounds__(512, 2) void k_gemm_out8(
    const u16* __restrict__ A, const u16* __restrict__ Bt,
    const float* __restrict__ xres, const float* __restrict__ ob,
    float* __restrict__ out) {
    __shared__ __align__(16) u16 lds[36864];        // 72KB -> 2 blocks/CU
    const int tid = threadIdx.x, lane = tid & 63;
    const int wm = (tid >> 6) >> 2, wn = (tid >> 6) & 3;

    // bijective XCD swizzle, grid (4, 128) = 512 wg
    int fid = (int)blockIdx.y * 4 + (int)blockIdx.x;
    int swz = (fid & 7) * 64 + (fid >> 3);
    const long bn = swz & 3, bm = swz >> 2;

    f32x4 acc[4][4] = {};
    pipe128(A + bm * 128 * 1024, Bt + bn * 256 * 1024, lds, acc, tid);

    const long rbase = bm * 128 + wm * 64;
    const int cbase = (int)bn * 256 + wn * 64;
#pragma unroll
    for (int n = 0; n < 4; ++n) {
        int col = cbase + n * 16 + (lane & 15);
        float o0 = ob[col];
#pragma unroll
        for (int m = 0; m < 4; ++m) {
            long row = rbase + m * 16 + ((lane >> 4) << 2);
#pragma unroll
            for (int i = 0; i < 4; ++i) {
                long o = (row + i) * 1024 + col;
                out[o] = acc[m][n][i] + o0 + xres[o];
            }
        }
    }
}

// ---------------- conversions ----------------

__global__ __launch_bounds__(256) void k_cvt_x(const float4* __restrict__ x,
                                               uint2* __restrict__ o, int n4) {
    int i = blockIdx.x * 256 + threadIdx.x;
    if (i < n4) {
        float4 v = x[i];
        uint2 r;
        r.x = (u32)f2bf(v.x) | ((u32)f2bf(v.y) << 16);
        r.y = (u32)f2bf(v.z) | ((u32)f2bf(v.w) << 16);
        o[i] = r;
    }
}

__global__ __launch_bounds__(256) void k_transpose_bf(const float* __restrict__ w,
                                                      u16* __restrict__ wt, int R, int C) {
    __shared__ float t[32][33];
    int c0 = blockIdx.x * 32, r0 = blockIdx.y * 32;
    int x = threadIdx.x & 31, y = threadIdx.x >> 5;
    for (int i = y; i < 32; i += 8) t[i][x] = w[(size_t)(r0 + i) * C + c0 + x];
    __syncthreads();
    for (int i = y; i < 32; i += 8) wt[(size_t)(c0 + i) * R + r0 + x] = f2bf(t[x][i]);
}

// Interleaved concat transpose: rows 32t..32t+15 = gate ch 16t..16t+15,
// rows 32t+16..32t+31 = inp, same channels.
__global__ __launch_bounds__(256) void k_transpose_cat(const float* __restrict__ gw,
                                                       const float* __restrict__ iw,
                                                       u16* __restrict__ wt, int K, int C) {
    __shared__ float t[32][33];
    int c0 = blockIdx.x * 32, r0 = blockIdx.y * 32;
    const float* w = blockIdx.z ? iw : gw;
    int x = threadIdx.x & 31, y = threadIdx.x >> 5;
    for (int i = y; i < 32; i += 8) t[i][x] = w[(size_t)(r0 + i) * C + c0 + x];
    __syncthreads();
    for (int i = y; i < 32; i += 8) {
        int ch = c0 + i;
        int r = ((ch >> 4) << 5) | ((int)blockIdx.z << 4) | (ch & 15);
        wt[(size_t)r * K + r0 + x] = f2bf(t[x][i]);
    }
}

// ---------------- chunked affine scan (packed ab stream) ----------------
// ab[row*1024 + ch]: lo = a (bf16), hi = b (bf16). h_t = a*h + b over s.

__global__ __launch_bounds__(256) void k_scanA(const u32* __restrict__ ab,
                                               float2* __restrict__ cAB) {
    int e = blockIdx.x * 256 + threadIdx.x;  // 0..1023
    int c = blockIdx.y, bt = blockIdx.z;
    long base = ((long)bt * 4096 + c * 64) * 1024 + e;
    float Aa = 1.f, H = 0.f;
#pragma unroll 4
    for (int i = 0; i < 64; ++i) {
        u32 v = ab[base + (long)i * 1024];
        float a = bf2f((u16)v), b = bf2f((u16)(v >> 16));
        H = a * H + b;
        Aa *= a;
    }
    cAB[((long)bt * 64 + c) * 1024 + e] = make_float2(Aa, H);
}

__global__ __launch_bounds__(256) void k_scanB(const float2* __restrict__ cAB,
                                               float* __restrict__ hin) {
    int e = blockIdx.x * 256 + threadIdx.x;
    int bt = blockIdx.y;
    float H = 0.f;
#pragma unroll
    for (int c = 0; c < 64; ++c) {
        long s = ((long)bt * 64 + c) * 1024 + e;
        hin[s] = H;
        float2 v = cAB[s];
        H = v.x * H + v.y;
    }
}

__global__ __launch_bounds__(256) void k_scanC(const u32* __restrict__ ab,
                                               const float* __restrict__ hin,
                                               u16* __restrict__ hout) {
    int e = blockIdx.x * 256 + threadIdx.x;
    int c = blockIdx.y, bt = blockIdx.z;
    long base = ((long)bt * 4096 + c * 64) * 1024 + e;
    float H = hin[((long)bt * 64 + c) * 1024 + e];
#pragma unroll 4
    for (int i = 0; i < 64; ++i) {
        u32 v = ab[base + (long)i * 1024];
        H = bf2f((u16)v) * H + bf2f((u16)(v >> 16));
        hout[base + (long)i * 1024] = f2bf(H);
    }
}

// ---------------- launch ----------------

extern "C" void kernel_launch(void* const* d_in, const int* in_sizes, int n_in,
                              void* d_out, int out_size, void* d_ws, size_t ws_size,
                              hipStream_t stream) {
    const float* x      = (const float*)d_in[0];
    const float* gate_w = (const float*)d_in[1];
    const float* gate_b = (const float*)d_in[2];
    const float* inp_w  = (const float*)d_in[3];
    const float* inp_b  = (const float*)d_in[4];
    const float* out_w  = (const float*)d_in[5];
    const float* out_b  = (const float*)d_in[6];
    float* out = (float*)d_out;

    const int Bsz = 4, S = 4096, Din = 1024, Dst = 1024;
    const int M = Bsz * S;                 // 16384
    const long nx = (long)M * Din;         // 16777216

    // workspace layout (bytes)
    char* w = (char*)d_ws;
    u16* xb      = (u16*)(w);                // 33,554,432  x bf16
    u16* catW    = (u16*)(w + 33554432);     //  4,194,304  [gate;inp] interleaved ^T
    u16* owT     = (u16*)(w + 37748736);     //  2,097,152  out_w^T bf16
    u16* hbf     = (u16*)(w + 39845888);     // 33,554,432  scan_out bf16
    float2* cAB  = (float2*)(w + 73400320);  //  2,097,152  chunk (A,H) pairs
    float* hin   = (float*)(w + 75497472);   //  1,048,576  chunk incoming states
    // total 76,546,048 B

    // packed ab lives in d_out (67,108,864 B); overwritten by final GEMM.
    u32* ab = (u32*)d_out;

    // 1. conversions
    k_cvt_x<<<(int)(nx / 4 / 256), 256, 0, stream>>>((const float4*)x, (uint2*)xb, (int)(nx / 4));
    k_transpose_cat<<<dim3(Dst / 32, Din / 32, 2), 256, 0, stream>>>(gate_w, inp_w, catW, Din, Dst);
    k_transpose_bf<<<dim3(Din / 32, Dst / 32), 256, 0, stream>>>(out_w, owT, Dst, Din);

    // 2. fused concat GEMM -> packed ab
    k_gemm_cat8<<<dim3(8, M / 256), 512, 0, stream>>>(xb, catW, gate_b, inp_b, ab);

    // 3. chunked scan -> h (bf16)
    k_scanA<<<dim3(4, 64, Bsz), 256, 0, stream>>>(ab, cAB);
    k_scanB<<<dim3(4, Bsz), 256, 0, stream>>>(cAB, hin);
    k_scanC<<<dim3(4, 64, Bsz), 256, 0, stream>>>(ab, hin, hbf);

    // 4. final GEMM: out = h @ out_w + x + out_b
    k_gemm_out8<<<dim3(4, M / 128), 512, 0, stream>>>(hbf, owT, x, out_b, out);
}